// Round 11
// baseline (111.112 us; speedup 1.0000x reference)
//
#include <hip/hip_runtime.h>
#include <math.h>

#define THREADS 256

// ============================================================================
// Sorted-axis direct decode (round-8 verified body) with the LAST untested
// structural cost removed: NO LDS, NO staging, NO __syncthreads.
// The codebook is only needed by the ~3e-4 slow path, which now reads
// grid/gnorm directly from global (L2-resident, bit-identical values and
// rounding order -> output unchanged). Fast path: load x -> compute -> store,
// with zero head-of-block serialization.
//   H-barrier: dur 78-85 (staging barrier was the hidden ~17us)
//   H-null:    dur 89-96 -> 6th structural null; declare ceiling next round.
// ============================================================================

// Rare (~3e-4): bit-exact emulation of the numpy reference.
// Sequential f32 dot (no FMA), 2*dot - gn, first-wins argmax.
// Reads the codebook from GLOBAL memory (L2/L1-cached; values identical to
// the former LDS copy, so results are bit-identical).
__device__ __noinline__ void exact_scan(float fx0, float fx1, float fx2, float fx3,
                                        const float4* __restrict__ gg,
                                        const float* __restrict__ gn,
                                        float4* g, float* fidx)
{
    float bexact = -INFINITY;
    int bk = 0;
    for (int k = 0; k < 256; ++k) {
        const float4 gk = gg[k];
        float d = __fmul_rn(fx0, gk.x);
        d = __fadd_rn(d, __fmul_rn(fx1, gk.y));
        d = __fadd_rn(d, __fmul_rn(fx2, gk.z));
        d = __fadd_rn(d, __fmul_rn(fx3, gk.w));
        const float sc = __fsub_rn(__fmul_rn(2.0f, d), gn[k]);
        if (sc > bexact) { bexact = sc; bk = k; }
    }
    *g = gg[bk];
    *fidx = (float)bk;
}

__global__ __launch_bounds__(THREADS)
void d4_fused_kernel(const float* __restrict__ X,
                     const float* __restrict__ grid,
                     const float* __restrict__ gnorm,
                     float* __restrict__ out, int n)
{
    const int i = blockIdx.x * blockDim.x + threadIdx.x;
    if (i >= n) return;

    const float4 xv = reinterpret_cast<const float4*>(X)[i];
    const float fx0 = xv.x, fx1 = xv.y, fx2 = xv.z, fx3 = xv.w;

    const float a0 = fabsf(fx0), a1 = fabsf(fx1), a2 = fabsf(fx2), a3 = fabsf(fx3);
    const int sg0 = (fx0 < 0.f) ? 1 : 0, sg1 = (fx1 < 0.f) ? 1 : 0;
    const int sg2 = (fx2 < 0.f) ? 1 : 0, sg3 = (fx3 < 0.f) ? 1 : 0;
    const int qp = (sg0 + sg1 + sg2 + sg3) & 1;   // minus-parity of optimal signs

    // ---- sort DESC with permutation (5 compare-exchanges) ----
    float v0 = a0, v1 = a1, v2 = a2, v3 = a3;
    int p0 = 0, p1 = 1, p2 = 2, p3 = 3;
#define CSW(x, y, ix, iy) { const bool lt_ = (x) < (y); \
    const float tf_ = x; x = lt_ ? y : x; y = lt_ ? tf_ : y; \
    const int ti_ = ix; ix = lt_ ? iy : ix; iy = lt_ ? ti_ : iy; }
    CSW(v0, v1, p0, p1) CSW(v2, v3, p2, p3) CSW(v0, v2, p0, p2)
    CSW(v1, v3, p1, p3) CSW(v1, v2, p1, p2)
#undef CSW

    // ---- 7 candidate scores (free-sign) ----
    const float A    = (v0 + v1) + (v2 + v3);
    const float base = A - 1.f;                       // id0
    const float r0v = (v0 + v0) - 2.f, r1v = (v1 + v1) - 2.f;
    const float r2v = (v2 + v2) - 2.f, r3v = (v3 + v3) - 2.f;
    const float z0v = ((v0 + v0) + (v0 + v0)) - 6.f;
    const float C1s = base + r0v;
    const float C2s = C1s + r1v;
    const float C3s = C2s + r2v;
    const float C4s = C3s + r3v;
    const float C5s = base + z0v;
    const float C6s = C5s + r1v;

    // parity penalties: candidates' min flip cost is exactly 0.5*v3 (1.5*v3
    // for id4); pattern parity (sum of codes mod 2): odd for ids {1,3,6}.
    const float twov3 = v3 + v3;
    const float pe = qp ? twov3 : 0.f;        // even-parity pattern, qp odd
    const float po = twov3 - pe;              // odd-parity pattern, qp even
    const float p4p = (pe + pe) + pe;         // id4: 6*v3 when qp odd
    const float e0 = base - pe;
    const float e1 = C1s - po;
    const float e2 = C2s - pe;
    const float e3 = C3s - po;
    const float e4 = C4s - p4p;
    const float e5 = C5s - pe;
    const float e6 = C6s - po;

    // ---- top-2 + argmax over 7 (merge second = med3(b1,b2,max(s1,s2))) ----
    const float bA = fmaxf(e0, e1), sA = fminf(e0, e1); const int iA = (e1 > e0) ? 1 : 0;
    const float bB = fmaxf(e2, e3), sB = fminf(e2, e3); const int iB = (e3 > e2) ? 3 : 2;
    const float bC = fmaxf(e4, e5), sC = fminf(e4, e5); const int iC = (e5 > e4) ? 5 : 4;
    const float bAB = fmaxf(bA, bB);
    const float sAB = __builtin_amdgcn_fmed3f(bA, bB, fmaxf(sA, sB));
    const int   iAB = (bB > bA) ? iB : iA;
    const float bCD = fmaxf(bC, e6);
    const float sCD = __builtin_amdgcn_fmed3f(bC, e6, sC);
    const int   iCD = (e6 > bC) ? 6 : iC;
    const float best   = fmaxf(bAB, bCD);
    const float second = __builtin_amdgcn_fmed3f(bAB, bCD, fmaxf(sAB, sCD));
    const int   id     = (bCD > bAB) ? iCD : iAB;

    // ---- certified gap ----
    const float d01 = v0 - v1, d12 = v1 - v2, d23 = v2 - v3;
    const float dadj = fminf(fminf(d01, d12), d23);
    const int flip = (((0x4A >> id) & 1) != qp) ? 1 : 0;   // parity mismatch
    // winner's two smallest flip costs: q1 = (id4?1.5:0.5)*v3, q2 per case
    const float q1 = ((id == 4) ? 1.5f : 0.5f) * v3;
    const float q2 = ((id == 3 || id == 4) ? 1.5f : 0.5f) * v2;
    const float within = flip ? (4.f * (q2 - q1)) : (4.f * (q1 + q2));
    const float gap = fminf(fminf(best - second, dadj + dadj), within);
    const float delta = 8e-6f * (A + 6.f);

    // ---- reconstruct codeword on original coordinates ----
    // codes at sorted positions, scattered through the permutation
    const int cs0 = (id >= 5) ? 2 : ((id >= 1) ? 1 : 0);
    const int cs1 = ((id >= 2 && id <= 4) || id == 6) ? 1 : 0;
    const int cs2 = (id == 3 || id == 4) ? 1 : 0;
    const int cs3 = (id == 4) ? 1 : 0;
    const unsigned mcb = ((unsigned)cs0 << (p0 + p0)) | ((unsigned)cs1 << (p1 + p1))
                       | ((unsigned)cs2 << (p2 + p2)) | ((unsigned)cs3 << (p3 + p3));
    const int c0 = mcb & 3, c1 = (mcb >> 2) & 3, c2 = (mcb >> 4) & 3, c3 = (mcb >> 6) & 3;
    const float m0 = 0.5f + (float)c0, m1 = 0.5f + (float)c1;
    const float m2 = 0.5f + (float)c2, m3 = 0.5f + (float)c3;

    // sign fix: flip exactly coordinate perm[3] on parity mismatch
    const bool n0 = (sg0 != 0) != (flip && p3 == 0);
    const bool n1 = (sg1 != 0) != (flip && p3 == 1);
    const bool n2 = (sg2 != 0) != (flip && p3 == 2);
    const bool n3 = (sg3 != 0) != (flip && p3 == 3);

    float4 g;
    g.x = n0 ? -m0 : m0;
    g.y = n1 ? -m1 : m1;
    g.z = n2 ? -m2 : m2;
    g.w = n3 ? -m3 : m3;

    // ---- reference i8 index from (id, permutation) ----
    // id2 pair {p0,p1}: contains 0 -> i8 = 2*(p0+p1)+1, else complement pair
    // {0,l}: i8 = 2*l = 12-2*(p0+p1).  (verified vs MCP table)
    const int sum01 = p0 + p1;
    const int mn01 = (p0 < p1) ? p0 : p1;
    const int i8_2 = (mn01 == 0) ? (sum01 + sum01 + 1) : (12 - (sum01 + sum01));
    const int i8_6 = 20 + ((p0 - ((p0 > p1) ? 1 : 0)) << 2) + p1;
    int i8v = i8_6;                                   // id6 default
    i8v = (id == 0) ? 0          : i8v;
    i8v = (id == 1) ? (8 + p0)   : i8v;
    i8v = (id == 2) ? i8_2       : i8v;
    i8v = (id == 3) ? (12 + p3)  : i8v;
    i8v = (id == 4) ? 1          : i8v;
    i8v = (id == 5) ? (16 + p0)  : i8v;

    // invert _code3_signs: b7=sign(g0), b6=sign(g1)^b7, b5=sign(g2)^b7
    const int b7 = n0 ? 1 : 0;
    const int b6 = (n1 ? 1 : 0) ^ b7;
    const int b5 = (n2 ? 1 : 0) ^ b7;
    float fidx = (float)(i8v | (b5 << 5) | (b6 << 6) | (b7 << 7));

    if (gap < delta) {
        exact_scan(fx0, fx1, fx2, fx3,
                   reinterpret_cast<const float4*>(grid), gnorm, &g, &fidx);
    }

    reinterpret_cast<float4*>(out)[i] = g;                 // output 0
    out[(size_t)4 * (size_t)n + (size_t)i] = fidx;         // output 1
}

extern "C" void kernel_launch(void* const* d_in, const int* in_sizes, int n_in,
                              void* d_out, int out_size, void* d_ws, size_t ws_size,
                              hipStream_t stream)
{
    const float* X = (const float*)d_in[0];
    const float* grid = (const float*)d_in[1];
    const float* gnorm = (const float*)d_in[2];
    float* out = (float*)d_out;
    const int n = in_sizes[0] / 4;
    const int blocks = (n + THREADS - 1) / THREADS;
    hipLaunchKernelGGL(d4_fused_kernel, dim3(blocks), dim3(THREADS), 0, stream,
                       X, grid, gnorm, out, n);
}

// Round 12
// 86.996 us; speedup vs baseline: 1.2772x; 1.2772x over previous
//
#include <hip/hip_runtime.h>
#include <math.h>

#define THREADS 256

// ============================================================================
// Sorted-axis direct decode (round-8 verified structure: LDS-staged codebook)
// with ONE change: the rare bit-exact slow path is INLINED into its divergent
// branch and writes its results directly into the SSA values g/fidx.
// Rationale (round-11 counters): the old __noinline__ exact_scan(&g,&fidx)
// made g/fidx address-taken -> unconditional per-thread scratch store+reload
// (WRITE_SIZE showed +20B/thread; VGPR collapsed to 16; T_k doubled when the
// pattern worsened). No address-taken locals remain in this kernel.
// ============================================================================

__global__ __launch_bounds__(THREADS)
void d4_fused_kernel(const float* __restrict__ X,
                     const float* __restrict__ grid,
                     const float* __restrict__ gnorm,
                     float* __restrict__ out, int n)
{
    // Stage codebook for the (rare) exact slow path; broadcast reads later.
    __shared__ float4 sgrid[256];
    __shared__ float  sgn[256];
    sgrid[threadIdx.x] = reinterpret_cast<const float4*>(grid)[threadIdx.x];
    sgn[threadIdx.x]   = gnorm[threadIdx.x];
    __syncthreads();

    const int i = blockIdx.x * blockDim.x + threadIdx.x;
    if (i >= n) return;

    const float4 xv = reinterpret_cast<const float4*>(X)[i];
    const float fx0 = xv.x, fx1 = xv.y, fx2 = xv.z, fx3 = xv.w;

    const float a0 = fabsf(fx0), a1 = fabsf(fx1), a2 = fabsf(fx2), a3 = fabsf(fx3);
    const int sg0 = (fx0 < 0.f) ? 1 : 0, sg1 = (fx1 < 0.f) ? 1 : 0;
    const int sg2 = (fx2 < 0.f) ? 1 : 0, sg3 = (fx3 < 0.f) ? 1 : 0;
    const int qp = (sg0 + sg1 + sg2 + sg3) & 1;   // minus-parity of optimal signs

    // ---- sort DESC with permutation (5 compare-exchanges) ----
    float v0 = a0, v1 = a1, v2 = a2, v3 = a3;
    int p0 = 0, p1 = 1, p2 = 2, p3 = 3;
#define CSW(x, y, ix, iy) { const bool lt_ = (x) < (y); \
    const float tf_ = x; x = lt_ ? y : x; y = lt_ ? tf_ : y; \
    const int ti_ = ix; ix = lt_ ? iy : ix; iy = lt_ ? ti_ : iy; }
    CSW(v0, v1, p0, p1) CSW(v2, v3, p2, p3) CSW(v0, v2, p0, p2)
    CSW(v1, v3, p1, p3) CSW(v1, v2, p1, p2)
#undef CSW

    // ---- 7 candidate scores (free-sign) ----
    const float A    = (v0 + v1) + (v2 + v3);
    const float base = A - 1.f;                       // id0
    const float r0v = (v0 + v0) - 2.f, r1v = (v1 + v1) - 2.f;
    const float r2v = (v2 + v2) - 2.f, r3v = (v3 + v3) - 2.f;
    const float z0v = ((v0 + v0) + (v0 + v0)) - 6.f;
    const float C1s = base + r0v;
    const float C2s = C1s + r1v;
    const float C3s = C2s + r2v;
    const float C4s = C3s + r3v;
    const float C5s = base + z0v;
    const float C6s = C5s + r1v;

    // parity penalties: candidates' min flip cost is exactly 0.5*v3 (1.5*v3
    // for id4); pattern parity (sum of codes mod 2): odd for ids {1,3,6}.
    const float twov3 = v3 + v3;
    const float pe = qp ? twov3 : 0.f;        // even-parity pattern, qp odd
    const float po = twov3 - pe;              // odd-parity pattern, qp even
    const float p4p = (pe + pe) + pe;         // id4: 6*v3 when qp odd
    const float e0 = base - pe;
    const float e1 = C1s - po;
    const float e2 = C2s - pe;
    const float e3 = C3s - po;
    const float e4 = C4s - p4p;
    const float e5 = C5s - pe;
    const float e6 = C6s - po;

    // ---- top-2 + argmax over 7 (merge second = med3(b1,b2,max(s1,s2))) ----
    const float bA = fmaxf(e0, e1), sA = fminf(e0, e1); const int iA = (e1 > e0) ? 1 : 0;
    const float bB = fmaxf(e2, e3), sB = fminf(e2, e3); const int iB = (e3 > e2) ? 3 : 2;
    const float bC = fmaxf(e4, e5), sC = fminf(e4, e5); const int iC = (e5 > e4) ? 5 : 4;
    const float bAB = fmaxf(bA, bB);
    const float sAB = __builtin_amdgcn_fmed3f(bA, bB, fmaxf(sA, sB));
    const int   iAB = (bB > bA) ? iB : iA;
    const float bCD = fmaxf(bC, e6);
    const float sCD = __builtin_amdgcn_fmed3f(bC, e6, sC);
    const int   iCD = (e6 > bC) ? 6 : iC;
    const float best   = fmaxf(bAB, bCD);
    const float second = __builtin_amdgcn_fmed3f(bAB, bCD, fmaxf(sAB, sCD));
    const int   id     = (bCD > bAB) ? iCD : iAB;

    // ---- certified gap ----
    const float d01 = v0 - v1, d12 = v1 - v2, d23 = v2 - v3;
    const float dadj = fminf(fminf(d01, d12), d23);
    const int flip = (((0x4A >> id) & 1) != qp) ? 1 : 0;   // parity mismatch
    // winner's two smallest flip costs: q1 = (id4?1.5:0.5)*v3, q2 per case
    const float q1 = ((id == 4) ? 1.5f : 0.5f) * v3;
    const float q2 = ((id == 3 || id == 4) ? 1.5f : 0.5f) * v2;
    const float within = flip ? (4.f * (q2 - q1)) : (4.f * (q1 + q2));
    const float gap = fminf(fminf(best - second, dadj + dadj), within);
    const float delta = 8e-6f * (A + 6.f);

    // ---- reconstruct codeword on original coordinates ----
    // codes at sorted positions, scattered through the permutation
    const int cs0 = (id >= 5) ? 2 : ((id >= 1) ? 1 : 0);
    const int cs1 = ((id >= 2 && id <= 4) || id == 6) ? 1 : 0;
    const int cs2 = (id == 3 || id == 4) ? 1 : 0;
    const int cs3 = (id == 4) ? 1 : 0;
    const unsigned mcb = ((unsigned)cs0 << (p0 + p0)) | ((unsigned)cs1 << (p1 + p1))
                       | ((unsigned)cs2 << (p2 + p2)) | ((unsigned)cs3 << (p3 + p3));
    const int c0 = mcb & 3, c1 = (mcb >> 2) & 3, c2 = (mcb >> 4) & 3, c3 = (mcb >> 6) & 3;
    const float m0 = 0.5f + (float)c0, m1 = 0.5f + (float)c1;
    const float m2 = 0.5f + (float)c2, m3 = 0.5f + (float)c3;

    // sign fix: flip exactly coordinate perm[3] on parity mismatch
    const bool n0 = (sg0 != 0) != (flip && p3 == 0);
    const bool n1 = (sg1 != 0) != (flip && p3 == 1);
    const bool n2 = (sg2 != 0) != (flip && p3 == 2);
    const bool n3 = (sg3 != 0) != (flip && p3 == 3);

    float gx = n0 ? -m0 : m0;
    float gy = n1 ? -m1 : m1;
    float gz = n2 ? -m2 : m2;
    float gw = n3 ? -m3 : m3;

    // ---- reference i8 index from (id, permutation) ----
    // id2 pair {p0,p1}: contains 0 -> i8 = 2*(p0+p1)+1, else complement pair
    // {0,l}: i8 = 2*l = 12-2*(p0+p1).  (verified vs MCP table)
    const int sum01 = p0 + p1;
    const int mn01 = (p0 < p1) ? p0 : p1;
    const int i8_2 = (mn01 == 0) ? (sum01 + sum01 + 1) : (12 - (sum01 + sum01));
    const int i8_6 = 20 + ((p0 - ((p0 > p1) ? 1 : 0)) << 2) + p1;
    int i8v = i8_6;                                   // id6 default
    i8v = (id == 0) ? 0          : i8v;
    i8v = (id == 1) ? (8 + p0)   : i8v;
    i8v = (id == 2) ? i8_2       : i8v;
    i8v = (id == 3) ? (12 + p3)  : i8v;
    i8v = (id == 4) ? 1          : i8v;
    i8v = (id == 5) ? (16 + p0)  : i8v;

    // invert _code3_signs: b7=sign(g0), b6=sign(g1)^b7, b5=sign(g2)^b7
    const int b7 = n0 ? 1 : 0;
    const int b6 = (n1 ? 1 : 0) ^ b7;
    const int b5 = (n2 ? 1 : 0) ^ b7;
    float fidx = (float)(i8v | (b5 << 5) | (b6 << 6) | (b7 << 7));

    if (gap < delta) {
        // Rare (~3e-4): bit-exact emulation of the numpy reference, INLINE.
        // Sequential f32 dot (no FMA), 2*dot - gn, first-wins argmax.
        // Results assigned directly to SSA values -- no address-taken locals.
        float bexact = -INFINITY;
        int bk = 0;
        for (int k = 0; k < 256; ++k) {
            const float4 gk = sgrid[k];
            float d = __fmul_rn(fx0, gk.x);
            d = __fadd_rn(d, __fmul_rn(fx1, gk.y));
            d = __fadd_rn(d, __fmul_rn(fx2, gk.z));
            d = __fadd_rn(d, __fmul_rn(fx3, gk.w));
            const float sc = __fsub_rn(__fmul_rn(2.0f, d), sgn[k]);
            if (sc > bexact) { bexact = sc; bk = k; }
        }
        const float4 ge = sgrid[bk];
        gx = ge.x; gy = ge.y; gz = ge.z; gw = ge.w;
        fidx = (float)bk;
    }

    float4 g; g.x = gx; g.y = gy; g.z = gz; g.w = gw;
    reinterpret_cast<float4*>(out)[i] = g;                 // output 0
    out[(size_t)4 * (size_t)n + (size_t)i] = fidx;         // output 1
}

extern "C" void kernel_launch(void* const* d_in, const int* in_sizes, int n_in,
                              void* d_out, int out_size, void* d_ws, size_t ws_size,
                              hipStream_t stream)
{
    const float* X = (const float*)d_in[0];
    const float* grid = (const float*)d_in[1];
    const float* gnorm = (const float*)d_in[2];
    float* out = (float*)d_out;
    const int n = in_sizes[0] / 4;
    const int blocks = (n + THREADS - 1) / THREADS;
    hipLaunchKernelGGL(d4_fused_kernel, dim3(blocks), dim3(THREADS), 0, stream,
                       X, grid, gnorm, out, n);
}